// Round 4
// baseline (600.207 us; speedup 1.0000x reference)
//
#include <hip/hip_runtime.h>

typedef float  f4   __attribute__((ext_vector_type(4)));
typedef __bf16 bf8_t __attribute__((ext_vector_type(8)));
typedef __bf16 bf4_t __attribute__((ext_vector_type(4)));

__device__ __forceinline__ void glds16(const void* g, void* l) {
    __builtin_amdgcn_global_load_lds(
        (const __attribute__((address_space(1))) void*)g,
        (__attribute__((address_space(3))) void*)l, 16, 0, 0);
}

// ---------------------------------------------------------------------------
// Positional encodings + combined projection bias (bc = 2*b_p1 + b_p2).
// ---------------------------------------------------------------------------
__global__ __launch_bounds__(256)
void pos_enc_kernel(float* __restrict__ P1, float* __restrict__ P2,
                    float* __restrict__ P3,
                    const float* __restrict__ bp1, const float* __restrict__ bp2,
                    float* __restrict__ bc) {
    int idx = blockIdx.x * 256 + threadIdx.x;
    const int n1 = 128 * 256, n2 = 128 * 512, n3 = 128 * 1280;
    const int nP = n1 + n2 + n3;
    if (idx >= nP) {
        int j = idx - nP;
        if (j < 32000) bc[j] = 2.f * bp1[j] + bp2[j];
        return;
    }
    float* P; int d, local;
    if (idx < n1)           { P = P1; d = 256;  local = idx; }
    else if (idx < n1 + n2) { P = P2; d = 512;  local = idx - n1; }
    else                    { P = P3; d = 1280; local = idx - n1 - n2; }
    int s = local / d;
    int k = local - s * d;
    int i = k >> 1;
    float expo = (-2.0f * (float)i) / (float)d;
    float ang  = (float)s * powf(10000.0f, expo);
    P[local] = (k & 1) ? cosf(ang) : sinf(ang);
}

// ---------------------------------------------------------------------------
// Fused transpose-to-bf16 prepass: dst[n][k] = (bf16)src[k][n] for 5 weights.
// 32x32 tiles via LDS. All dims are multiples of 32.
// ---------------------------------------------------------------------------
__global__ __launch_bounds__(256)
void transpose_bf16_k(const float* __restrict__ Wemb, __bf16* __restrict__ WembT,
                      const float* __restrict__ Wd2, __bf16* __restrict__ Wd2T,
                      const float* __restrict__ Wp1, __bf16* __restrict__ Wp1T,
                      const float* __restrict__ Wp2, __bf16* __restrict__ Wp2T,
                      const float* __restrict__ Wp3, __bf16* __restrict__ Wp3T) {
    const int bid = blockIdx.x;
    const float* src; __bf16* dst; int CN, RK, tn, local;
    if (bid < 4000)      { src = Wemb; dst = WembT; RK = 32000; CN = 128; tn = 4;  local = bid; }
    else if (bid < 4320) { src = Wd2;  dst = Wd2T;  RK = 640;   CN = 512; tn = 16; local = bid - 4000; }
    else if (bid < 4352) { src = Wp1;  dst = Wp1T;  RK = 256;   CN = 128; tn = 4;  local = bid - 4320; }
    else if (bid < 4480) { src = Wp2;  dst = Wp2T;  RK = 512;   CN = 256; tn = 8;  local = bid - 4352; }
    else                 { src = Wp3;  dst = Wp3T;  RK = 1280;  CN = 640; tn = 20; local = bid - 4480; }
    const int kt = local / tn, ntl = local - kt * tn;
    const int k0 = kt * 32, n0 = ntl * 32;
    __shared__ float tile[32][33];
    const int t = threadIdx.x;
    const int r = t >> 3, c4 = (t & 7) * 4;
    const f4 v = *(const f4*)(src + (long)(k0 + r) * CN + n0 + c4);
    tile[r][c4] = v[0]; tile[r][c4 + 1] = v[1];
    tile[r][c4 + 2] = v[2]; tile[r][c4 + 3] = v[3];
    __syncthreads();
    bf4_t o;
    o[0] = (__bf16)tile[c4][r];     o[1] = (__bf16)tile[c4 + 1][r];
    o[2] = (__bf16)tile[c4 + 2][r]; o[3] = (__bf16)tile[c4 + 3][r];
    *(bf4_t*)(dst + (long)(n0 + r) * RK + k0 + c4) = o;
}

// ---------------------------------------------------------------------------
// MFMA GEMM v2 (m97 structure): global_load_lds staging, linear LDS with
// source-side XOR swizzle, fp32->bf16 cvt at frag read. 2-barrier K-loop.
//   BMODE 0: B = bf16 [N][K] pre-transposed (ldb = row stride in elements)
//   BMODE 1: B = fp32 [K][N] natural (ldb = N row stride); frag via b32 reads
//   A: fp32 [M][K] (lda), M % 64 == 0. Tile BM=64 x BN=128, BK=32, 4 waves.
//   ksplit>1: fp32 partials C[(batch*ksplit+kz)*M*N]; epilogue deferred.
//   xcdmap: 1-D grid 1024 = 32 bm x 32 kz, k-slices grouped per XCD.
// ---------------------------------------------------------------------------
template<int BMODE>
__global__ __launch_bounds__(256)
void gemm_v2(const float* __restrict__ A, const void* __restrict__ Bv,
             float* __restrict__ C, const float* __restrict__ bias,
             const float* __restrict__ addsrc,
             int M, int N, int K, int lda, int ldb, int ldc,
             long sA, long sB, long sC, int ksplit, int kchunk, int relu,
             int xcdmap) {
    __shared__ __align__(16) float AsF[2048];                 // 8 KB
    __shared__ __align__(16) float Bbuf[BMODE ? 4096 : 2048]; // 16/8 KB
    __bf16* BsT = (__bf16*)Bbuf;

    const int t = threadIdx.x;
    int bn, bm, bz;
    if (xcdmap) {
        const int lin = blockIdx.x;
        const int xc = lin & 7, j = lin >> 3;
        bz = xc + ((j >> 5) << 3);
        bm = j & 31;
        bn = 0;
    } else { bn = blockIdx.x; bm = blockIdx.y; bz = blockIdx.z; }
    const int batch = bz / ksplit;
    const int kz = bz - batch * ksplit;
    const int m0 = bm * 64, n0 = bn * 128;
    const int kb = kz * kchunk;
    const int ke = (kb + kchunk < K) ? (kb + kchunk) : K;

    const int lane = t & 63;
    const int w = t >> 6;
    const int wm = w >> 1, wn = w & 1;
    const int fr = lane & 15;
    const int fq = (lane >> 4) * 8;

    f4 acc[2][4];
#pragma unroll
    for (int mt = 0; mt < 2; ++mt)
#pragma unroll
        for (int nt = 0; nt < 4; ++nt) acc[mt][nt] = (f4){0.f, 0.f, 0.f, 0.f};

    const float* Ab = A + (long)batch * sA;

    // A staging: chunk c = issue*256+t; r = c>>3; j = (c&7) ^ (r&7); 16B/lane
    const int ra = t >> 3;
    const int ja = (t & 7) ^ (ra & 7);     // same for both issues (r+32: &7 eq)
    const float* aS0 = Ab + (long)(m0 + ra) * lda + 4 * ja;
    const float* aS1 = aS0 + 32L * lda;
    float* aD0 = AsF + t * 4;
    float* aD1 = AsF + 1024 + t * 4;

    // B staging
    const __bf16* bTS0 = nullptr; const __bf16* bTS1 = nullptr;
    const float* bNS0 = nullptr;
    float* bD0 = Bbuf + t * 4;
    float* bD1 = Bbuf + 1024 + t * 4;
    float* bD2 = nullptr; float* bD3 = nullptr;
    if constexpr (BMODE == 0) {
        const __bf16* BT = (const __bf16*)Bv + (long)batch * sB;
        const int nb = t >> 2;
        const int fb = (nb & 3) ^ ((nb >> 2) & 3);
        const int jb = (t & 3) ^ fb;       // same xor for issue1 (n+64)
        bTS0 = BT + (long)(n0 + nb) * ldb + 8 * jb;
        bTS1 = bTS0 + 64L * ldb;
    } else {
        const float* Bn = (const float*)Bv + (long)batch * sB;
        bNS0 = Bn + (long)(t >> 5) * ldb + n0 + (t & 31) * 4;
        bD2 = Bbuf + 2048 + t * 4;
        bD3 = Bbuf + 3072 + t * 4;
    }

    // LDS frag-read offsets (constant across K)
    const int R0 = wm * 32 + fr, R1 = R0 + 16;
    const int jq = (lane >> 4) * 2;
    const int x7 = R0 & 7;                 // == R1 & 7
    const int aO00 = (R0 * 8 + (jq ^ x7)) * 4;
    const int aO01 = (R0 * 8 + ((jq + 1) ^ x7)) * 4;
    const int aO10 = (R1 * 8 + (jq ^ x7)) * 4;
    const int aO11 = (R1 * 8 + ((jq + 1) ^ x7)) * 4;
    int bOf[4];
    if constexpr (BMODE == 0) {
        const int fbc = (fr & 3) ^ ((fr >> 2) & 3);
        const int jb2 = (lane >> 4) ^ fbc;
#pragma unroll
        for (int nt = 0; nt < 4; ++nt)
            bOf[nt] = ((wn * 64 + nt * 16 + fr) * 4 + jb2) * 8;  // bf16 idx
    } else {
#pragma unroll
        for (int nt = 0; nt < 4; ++nt)
            bOf[nt] = wn * 64 + nt * 16 + fr;                    // col idx
    }

    for (int k0 = kb; k0 < ke; k0 += 32) {
        __syncthreads();                       // prev frag reads done
        glds16(aS0 + k0, aD0);
        glds16(aS1 + k0, aD1);
        if constexpr (BMODE == 0) {
            glds16(bTS0 + k0, bD0);
            glds16(bTS1 + k0, bD1);
        } else {
            const float* bp = bNS0 + (long)k0 * ldb;
            glds16(bp,            bD0);
            glds16(bp + 8L * ldb, bD1);
            glds16(bp + 16L * ldb, bD2);
            glds16(bp + 24L * ldb, bD3);
        }
        __syncthreads();                       // vmcnt(0) drain + barrier

        f4 x0 = *(const f4*)(AsF + aO00);
        f4 x1 = *(const f4*)(AsF + aO01);
        f4 x2 = *(const f4*)(AsF + aO10);
        f4 x3 = *(const f4*)(AsF + aO11);
        bf8_t af0, af1;
#pragma unroll
        for (int i = 0; i < 4; ++i) {
            af0[i] = (__bf16)x0[i]; af0[4 + i] = (__bf16)x1[i];
            af1[i] = (__bf16)x2[i]; af1[4 + i] = (__bf16)x3[i];
        }
#pragma unroll
        for (int nt = 0; nt < 4; ++nt) {
            bf8_t bv;
            if constexpr (BMODE == 0) {
                bv = *(const bf8_t*)(BsT + bOf[nt]);
            } else {
                const float* bb = Bbuf + fq * 128 + bOf[nt];
#pragma unroll
                for (int d = 0; d < 8; ++d) bv[d] = (__bf16)bb[d * 128];
            }
            acc[0][nt] = __builtin_amdgcn_mfma_f32_16x16x32_bf16(af0, bv, acc[0][nt], 0, 0, 0);
            acc[1][nt] = __builtin_amdgcn_mfma_f32_16x16x32_bf16(af1, bv, acc[1][nt], 0, 0, 0);
        }
    }

    float* Cp; long ldcp;
    const bool fin = (ksplit == 1);
    if (!fin) { Cp = C + (long)(batch * ksplit + kz) * M * N; ldcp = N; }
    else      { Cp = C + (long)batch * sC;                    ldcp = ldc; }

    const int rb = m0 + wm * 32 + (lane >> 4) * 4;
    const int cb_ = n0 + wn * 64 + fr;
#pragma unroll
    for (int mt = 0; mt < 2; ++mt) {
#pragma unroll
        for (int nt = 0; nt < 4; ++nt) {
            const int c = cb_ + nt * 16;
            const float bvl = (fin && bias) ? bias[c] : 0.f;
#pragma unroll
            for (int v = 0; v < 4; ++v) {
                const int r = rb + mt * 16 + v;
                float val = acc[mt][nt][v] + bvl;
                if (fin && relu) val = fmaxf(val, 0.f);
                if (fin && addsrc) val += addsrc[(long)r * ldcp + c];
                Cp[(long)r * ldcp + c] = val;
            }
        }
    }
}

// ---------------------------------------------------------------------------
// Skinny GEMM, M=16 exactly (fp32 VALU, column-parallel, HBM-bound):
//   C[m][n] = sum_k (Aa[m][k] (+Ab[m][k])) * B1[k][n]
//           (+ sum_k A2[m][k] * B2[k][n]) (+ bias[n]) [relu]
//   lda == K, ldb == N. Block: 128 cols (2/lane), 4 waves split K.
//   ksplit>1: fp32 partials C[(kz*16+m)*N + n], epilogue deferred.
// ---------------------------------------------------------------------------
__global__ __launch_bounds__(256)
void skinny16(const float* __restrict__ Aa, const float* __restrict__ Abp,
              const float* __restrict__ B1,
              const float* __restrict__ A2, const float* __restrict__ B2,
              float* __restrict__ C, const float* __restrict__ bias,
              int K, int N, int nblkn, int ksplit, int relu) {
    const int bid = blockIdx.x;
    const int nb = bid % nblkn;
    const int kz = bid / nblkn;
    const int t = threadIdx.x, w = t >> 6, lane = t & 63;
    const int col = nb * 128 + lane * 2;
    const int kchunk = K / ksplit;
    const int kpw = kchunk >> 2;
    const int ks = kz * kchunk + w * kpw;
    const int keL = ks + kpw;

    float ax[16], ay[16];
#pragma unroll
    for (int m = 0; m < 16; ++m) { ax[m] = 0.f; ay[m] = 0.f; }

    if (!Abp) {
#pragma unroll 4
        for (int k = ks; k < keL; ++k) {
            const float2 wv = *(const float2*)(B1 + (long)k * N + col);
#pragma unroll
            for (int m = 0; m < 16; ++m) {
                const float a = Aa[m * K + k];
                ax[m] += a * wv.x; ay[m] += a * wv.y;
            }
        }
    } else {
#pragma unroll 4
        for (int k = ks; k < keL; ++k) {
            const float2 wv = *(const float2*)(B1 + (long)k * N + col);
#pragma unroll
            for (int m = 0; m < 16; ++m) {
                const float a = Aa[m * K + k] + Abp[m * K + k];
                ax[m] += a * wv.x; ay[m] += a * wv.y;
            }
        }
    }
    if (B2) {
#pragma unroll 4
        for (int k = ks; k < keL; ++k) {
            const float2 wv = *(const float2*)(B2 + (long)k * N + col);
#pragma unroll
            for (int m = 0; m < 16; ++m) {
                const float a = A2[m * K + k];
                ax[m] += a * wv.x; ay[m] += a * wv.y;
            }
        }
    }

    __shared__ float redx[4][16][64];
    __shared__ float redy[4][16][64];
#pragma unroll
    for (int m = 0; m < 16; ++m) {
        redx[w][m][lane] = ax[m];
        redy[w][m][lane] = ay[m];
    }
    __syncthreads();
#pragma unroll
    for (int mm = 0; mm < 4; ++mm) {
        const int m = (t >> 6) * 4 + mm;
        const int l2 = t & 63;
        float sx = redx[0][m][l2] + redx[1][m][l2] + redx[2][m][l2] + redx[3][m][l2];
        float sy = redy[0][m][l2] + redy[1][m][l2] + redy[2][m][l2] + redy[3][m][l2];
        const int c2 = nb * 128 + l2 * 2;
        if (ksplit == 1) {
            if (bias) { sx += bias[c2]; sy += bias[c2 + 1]; }
            if (relu) { sx = fmaxf(sx, 0.f); sy = fmaxf(sy, 0.f); }
            C[(long)m * N + c2] = sx;
            C[(long)m * N + c2 + 1] = sy;
        } else {
            const long base = ((long)(kz * 16 + m)) * N + c2;
            C[base] = sx; C[base + 1] = sy;
        }
    }
}

// out[idx] = [relu](sum_z part[z*MN+idx] + bias[idx%N]) + addsrc[idx%addmod]
__global__ __launch_bounds__(256)
void reduce_splitk(const float* __restrict__ part, float* __restrict__ outp,
                   const float* __restrict__ bias, const float* __restrict__ addsrc,
                   int MN, int N, int addmod, int ksplit, int relu) {
    int idx = blockIdx.x * 256 + threadIdx.x;
    if (idx >= MN) return;
    float s = 0.f;
    for (int z = 0; z < ksplit; ++z) s += part[(long)z * MN + idx];
    if (bias) s += bias[idx % N];
    if (relu) s = fmaxf(s, 0.f);
    if (addsrc) s += addsrc[idx % addmod];
    outp[idx] = s;
}

// Fused GEMM1 reduce: h1 = relu(sum_z part + b_emb) + Q1; rs1 = rowsum(h1).
__global__ __launch_bounds__(256)
void reduce_rs_kernel(const float* __restrict__ part, float* __restrict__ h1,
                      const float* __restrict__ bias, const float* __restrict__ Q1,
                      float* __restrict__ rs1, int ksplit) {
    const int t = threadIdx.x;
    const int idx = blockIdx.x * 256 + t;
    float s = 0.f;
    for (int z = 0; z < ksplit; ++z) s += part[(long)z * 262144 + idx];
    s += bias[idx & 127];
    s = fmaxf(s, 0.f);
    s += Q1[idx & 16383];
    h1[idx] = s;
    float r = s;
    for (int off = 32; off > 0; off >>= 1) r += __shfl_down(r, off, 64);
    __shared__ float p[4];
    const int w = t >> 6, lane = t & 63;
    if (lane == 0) p[w] = r;
    __syncthreads();
    if (t < 2) rs1[(blockIdx.x << 1) + t] = p[t * 2] + p[t * 2 + 1];
}

// one wave per row: rs[r] = sum_j h[r*D + j]
__global__ __launch_bounds__(256)
void rowsum_kernel(const float* __restrict__ h, float* __restrict__ rs,
                   int rows, int D) {
    int gw = (blockIdx.x * 256 + threadIdx.x) >> 6;
    int lane = threadIdx.x & 63;
    if (gw >= rows) return;
    const float* p = h + (long)gw * D;
    float s = 0.f;
    for (int j = lane; j < D; j += 64) s += p[j];
    for (int off = 32; off > 0; off >>= 1) s += __shfl_down(s, off, 64);
    if (lane == 0) rs[gw] = s;
}

// ---------------------------------------------------------------------------
extern "C" void kernel_launch(void* const* d_in, const int* in_sizes, int n_in,
                              void* d_out, int out_size, void* d_ws, size_t ws_size,
                              hipStream_t stream) {
    const float* x       = (const float*)d_in[0];
    const float* W_emb   = (const float*)d_in[1];
    const float* b_emb   = (const float*)d_in[2];
    const float* W_pos1  = (const float*)d_in[3];
    const float* b_pos1  = (const float*)d_in[4];
    const float* W_red   = (const float*)d_in[5];
    const float* b_red   = (const float*)d_in[6];
    const float* W_pos2  = (const float*)d_in[7];
    const float* b_pos2  = (const float*)d_in[8];
    const float* W_red2  = (const float*)d_in[9];
    const float* b_red2  = (const float*)d_in[10];
    const float* W_pos3  = (const float*)d_in[11];
    const float* b_pos3  = (const float*)d_in[12];
    const float* W_down2 = (const float*)d_in[13];
    const float* b_down2 = (const float*)d_in[14];
    const float* W_flat  = (const float*)d_in[15];
    const float* b_flat  = (const float*)d_in[16];
    const float* W_d1    = (const float*)d_in[17];
    const float* b_d1    = (const float*)d_in[18];
    const float* W_d2    = (const float*)d_in[19];
    const float* b_d2    = (const float*)d_in[20];
    const float* W_d3    = (const float*)d_in[21];
    const float* b_d3    = (const float*)d_in[22];
    const float* W_p1    = (const float*)d_in[23];
    const float* b_p1    = (const float*)d_in[24];
    const float* W_p2    = (const float*)d_in[25];
    const float* b_p2    = (const float*)d_in[26];
    float* out = (float*)d_out;
    float* ws  = (float*)d_ws;

    size_t o = 0;
    auto alloc = [&](size_t n) { size_t p = o; o += (n + 63) & ~(size_t)63; return p; };
    const size_t oP1 = alloc(128 * 256);
    const size_t oP2 = alloc(128 * 512);
    const size_t oP3 = alloc(128 * 1280);
    const size_t oQ1 = alloc(128 * 128);
    const size_t oQ2 = alloc(128 * 256);
    const size_t oQ3 = alloc(128 * 640);
    const size_t oBC = alloc(32000);
    const size_t oH1 = alloc(2048 * 128);
    const size_t oRS1 = alloc(2048);
    const size_t oRS2 = alloc(2048);
    const size_t oH2 = alloc(2048 * 256);
    const size_t oH3 = alloc(2048 * 640);
    const size_t oH4 = alloc(2048 * 512);
    const size_t oH5 = alloc(16 * 512);
    const size_t oH6 = alloc(16 * 512);
    const size_t oH7 = alloc(16 * 512);
    const size_t oH8 = alloc(16 * 512);
    const size_t oM1 = alloc(16 * 32768);
    const size_t oM2 = alloc(16 * 163840);
    // bf16 transposed weights (sized in floats = bf16_count/2)
    const size_t oWembT = alloc(2048000);
    const size_t oWd2T  = alloc(163840);
    const size_t oP1T   = alloc(16384);
    const size_t oP2T   = alloc(65536);
    const size_t oP3T   = alloc(409600);
    // partials region: Q3(4x81920) -> GEMM1(32x262144) -> W_flat(32x8192)
    const size_t oRegA = alloc(32u * 262144);
    const size_t oPartQ3 = oRegA, oPartG1 = oRegA, oPartF = oRegA;
    (void)ws_size; (void)in_sizes; (void)n_in; (void)out_size;

    __bf16* WembT = (__bf16*)(ws + oWembT);
    __bf16* Wd2T  = (__bf16*)(ws + oWd2T);
    __bf16* P1T   = (__bf16*)(ws + oP1T);
    __bf16* P2T   = (__bf16*)(ws + oP2T);
    __bf16* P3T   = (__bf16*)(ws + oP3T);

    dim3 blk(256);

    // 1. positional encodings + combined bias; weight transposes (independent)
    pos_enc_kernel<<<dim3(1149), blk, 0, stream>>>(ws + oP1, ws + oP2, ws + oP3,
                                                   b_p1, b_p2, ws + oBC);
    transpose_bf16_k<<<dim3(5280), blk, 0, stream>>>(W_emb, WembT, W_down2, Wd2T,
                                                     W_pos1, P1T, W_pos2, P2T,
                                                     W_pos3, P3T);
    // 2-4. pos projections Q = relu(P @ W_pos + b)
    gemm_v2<0><<<dim3(1, 2, 1), blk, 0, stream>>>(ws + oP1, P1T, ws + oQ1,
        b_pos1, nullptr, 128, 128, 256, 256, 256, 128, 0, 0, 0, 1, 256, 1, 0);
    gemm_v2<0><<<dim3(2, 2, 1), blk, 0, stream>>>(ws + oP2, P2T, ws + oQ2,
        b_pos2, nullptr, 128, 256, 512, 512, 512, 256, 0, 0, 0, 1, 512, 1, 0);
    gemm_v2<0><<<dim3(5, 2, 4), blk, 0, stream>>>(ws + oP3, P3T, ws + oPartQ3,
        nullptr, nullptr, 128, 640, 1280, 1280, 1280, 640, 0, 0, 0, 4, 320, 0, 0);
    reduce_splitk<<<dim3(320), blk, 0, stream>>>(ws + oPartQ3, ws + oQ3, b_pos3,
                                                 nullptr, 81920, 640, 1, 4, 1);
    // 5. GEMM1: x(2048x32000) @ W_emb -> partials (split-K 32, XCD-grouped)
    gemm_v2<0><<<dim3(1024), blk, 0, stream>>>(x, WembT, ws + oPartG1,
        nullptr, nullptr, 2048, 128, 32000, 32000, 32000, 128, 0, 0, 0, 32, 1024, 0, 1);
    // 6. h1 = relu(sum + b_emb) + Q1 ; rs1 = rowsum(h1)
    reduce_rs_kernel<<<dim3(1024), blk, 0, stream>>>(ws + oPartG1, ws + oH1, b_emb,
                                                     ws + oQ1, ws + oRS1, 32);
    // 7. M1 = rs1(16x128) @ W_red viewed (128 x 32768)  [fp32 skinny]
    skinny16<<<dim3(256), blk, 0, stream>>>(ws + oRS1, nullptr, W_red,
        nullptr, nullptr, ws + oM1, nullptr, 128, 32768, 256, 1, 0);
    // 8. h2 = relu(h1[b] @ M1[b] + b_red) + Q2  (batched, fp32-natural B)
    gemm_v2<1><<<dim3(2, 2, 16), blk, 0, stream>>>(ws + oH1, ws + oM1, ws + oH2,
        b_red, ws + oQ2, 128, 256, 128, 128, 256, 256, 16384, 32768, 32768, 1, 128, 1, 0);
    // 9. rs2
    rowsum_kernel<<<dim3(512), blk, 0, stream>>>(ws + oH2, ws + oRS2, 2048, 256);
    // 10. M2 = rs2(16x128) @ W_red2 viewed (128 x 163840)
    skinny16<<<dim3(1280), blk, 0, stream>>>(ws + oRS2, nullptr, W_red2,
        nullptr, nullptr, ws + oM2, nullptr, 128, 163840, 1280, 1, 0);
    // 11. h3 = relu(h2[b] @ M2[b] + b_red2) + Q3  (batched)
    gemm_v2<1><<<dim3(5, 2, 16), blk, 0, stream>>>(ws + oH2, ws + oM2, ws + oH3,
        b_red2, ws + oQ3, 128, 640, 256, 256, 640, 640, 32768, 163840, 81920, 1, 256, 1, 0);
    // 12. h4 = relu(h3 @ W_down2 + b_down2)
    gemm_v2<0><<<dim3(4, 32, 1), blk, 0, stream>>>(ws + oH3, Wd2T, ws + oH4,
        b_down2, nullptr, 2048, 512, 640, 640, 640, 512, 0, 0, 0, 1, 640, 1, 0);
    // 13-14. h5 = relu(h4 viewed (16x65536) @ W_flat + b_flat)  [skinny, ks=32]
    skinny16<<<dim3(128), blk, 0, stream>>>(ws + oH4, nullptr, W_flat,
        nullptr, nullptr, ws + oPartF, nullptr, 65536, 512, 4, 32, 0);
    reduce_splitk<<<dim3(32), blk, 0, stream>>>(ws + oPartF, ws + oH5, b_flat,
                                                nullptr, 8192, 512, 1, 32, 1);
    // 15-17. dense chain [skinny]
    skinny16<<<dim3(4), blk, 0, stream>>>(ws + oH5, nullptr, W_d1,
        nullptr, nullptr, ws + oH6, b_d1, 512, 512, 4, 1, 1);
    skinny16<<<dim3(4), blk, 0, stream>>>(ws + oH6, nullptr, W_d2,
        nullptr, nullptr, ws + oH7, b_d2, 512, 512, 4, 1, 1);
    skinny16<<<dim3(4), blk, 0, stream>>>(ws + oH7, nullptr, W_d3,
        nullptr, nullptr, ws + oH8, b_d3, 512, 512, 4, 1, 1);
    // 18. out = (h6+h8)@W_p1 + h7@W_p2 + (2*b_p1 + b_p2)  [fused skinny]
    skinny16<<<dim3(250), blk, 0, stream>>>(ws + oH6, ws + oH8, W_p1,
        ws + oH7, W_p2, out, ws + oBC, 512, 32000, 250, 1, 0);
}

// Round 5
// 448.097 us; speedup vs baseline: 1.3395x; 1.3395x over previous
//
#include <hip/hip_runtime.h>

typedef float  f4   __attribute__((ext_vector_type(4)));
typedef __bf16 bf8_t __attribute__((ext_vector_type(8)));
typedef __bf16 bf4_t __attribute__((ext_vector_type(4)));

__device__ __forceinline__ void glds16(const void* g, void* l) {
    __builtin_amdgcn_global_load_lds(
        (const __attribute__((address_space(1))) void*)g,
        (__attribute__((address_space(3))) void*)l, 16, 0, 0);
}

// ---------------------------------------------------------------------------
// Positional encodings + combined projection bias (bc = 2*b_p1 + b_p2).
// ---------------------------------------------------------------------------
__global__ __launch_bounds__(256)
void pos_enc_kernel(float* __restrict__ P1, float* __restrict__ P2,
                    float* __restrict__ P3,
                    const float* __restrict__ bp1, const float* __restrict__ bp2,
                    float* __restrict__ bc) {
    int idx = blockIdx.x * 256 + threadIdx.x;
    const int n1 = 128 * 256, n2 = 128 * 512, n3 = 128 * 1280;
    const int nP = n1 + n2 + n3;
    if (idx >= nP) {
        int j = idx - nP;
        if (j < 32000) bc[j] = 2.f * bp1[j] + bp2[j];
        return;
    }
    float* P; int d, local;
    if (idx < n1)           { P = P1; d = 256;  local = idx; }
    else if (idx < n1 + n2) { P = P2; d = 512;  local = idx - n1; }
    else                    { P = P3; d = 1280; local = idx - n1 - n2; }
    int s = local / d;
    int k = local - s * d;
    int i = k >> 1;
    float expo = (-2.0f * (float)i) / (float)d;
    float ang  = (float)s * powf(10000.0f, expo);
    P[local] = (k & 1) ? cosf(ang) : sinf(ang);
}

// ---------------------------------------------------------------------------
// Transpose-to-bf16 prepass: dst[n][k] = (bf16)src[k][n] for
// W_emb, W_down2, W_pos1, W_pos2, W_pos3 (feeds BMODE0 GEMMs). 32x32 tiles.
// ---------------------------------------------------------------------------
__global__ __launch_bounds__(256)
void transpose_bf16_k(const float* __restrict__ Wemb, __bf16* __restrict__ WembT,
                      const float* __restrict__ Wd2, __bf16* __restrict__ Wd2T,
                      const float* __restrict__ Wq1, __bf16* __restrict__ Wq1T,
                      const float* __restrict__ Wq2, __bf16* __restrict__ Wq2T,
                      const float* __restrict__ Wq3, __bf16* __restrict__ Wq3T) {
    const int bid = blockIdx.x;
    const float* src; __bf16* dst; int CN, RK, tn, local;
    if (bid < 4000)      { src = Wemb; dst = WembT; RK = 32000; CN = 128; tn = 4;  local = bid; }
    else if (bid < 4320) { src = Wd2;  dst = Wd2T;  RK = 640;   CN = 512; tn = 16; local = bid - 4000; }
    else if (bid < 4352) { src = Wq1;  dst = Wq1T;  RK = 256;   CN = 128; tn = 4;  local = bid - 4320; }
    else if (bid < 4480) { src = Wq2;  dst = Wq2T;  RK = 512;   CN = 256; tn = 8;  local = bid - 4352; }
    else                 { src = Wq3;  dst = Wq3T;  RK = 1280;  CN = 640; tn = 20; local = bid - 4480; }
    const int kt = local / tn, ntl = local - kt * tn;
    const int k0 = kt * 32, n0 = ntl * 32;
    __shared__ float tile[32][33];
    const int t = threadIdx.x;
    const int r = t >> 3, c4 = (t & 7) * 4;
    const f4 v = *(const f4*)(src + (long)(k0 + r) * CN + n0 + c4);
    tile[r][c4] = v[0]; tile[r][c4 + 1] = v[1];
    tile[r][c4 + 2] = v[2]; tile[r][c4 + 3] = v[3];
    __syncthreads();
    bf4_t o2;
    o2[0] = (__bf16)tile[c4][r];     o2[1] = (__bf16)tile[c4 + 1][r];
    o2[2] = (__bf16)tile[c4 + 2][r]; o2[3] = (__bf16)tile[c4 + 3][r];
    *(bf4_t*)(dst + (long)(n0 + r) * RK + k0 + c4) = o2;
}

// ---------------------------------------------------------------------------
// MFMA GEMM v2, pipelined 2-phase (verified minimum recipe):
//   per iter: STAGE(buf[cur^1], k+32) | frag-read+MFMA from buf[cur] |
//   __syncthreads() (its vmcnt(0) drain waits loads issued one phase earlier).
//   BMODE 0: B = bf16 [N][K] pre-transposed; BMODE 1: B = fp32 [K][N] natural.
//   A: fp32 [M][K]. Tile BM=64 x BN=128, BK=32, 4 waves. M<64 handled by
//   lane-masked staging (junk rows discarded at epilogue).
//   ksplit>1: fp32 partials C[(batch*ksplit+kz)*M*N]; epilogue deferred.
//   xcdmap: 1-D grid 1024 = 32 bm x 32 kz, k-slices grouped per XCD.
// ---------------------------------------------------------------------------
template<int BMODE>
__global__ __launch_bounds__(256)
void gemm_v2(const float* __restrict__ A, const void* __restrict__ Bv,
             float* __restrict__ C, const float* __restrict__ bias,
             const float* __restrict__ addsrc,
             int M, int N, int K, int lda, int ldb, int ldc,
             long sA, long sB, long sC, int ksplit, int kchunk, int relu,
             int xcdmap) {
    __shared__ __align__(16) float AsF[2][2048];                  // 2 x 8 KB
    __shared__ __align__(16) float Bbuf[2][BMODE ? 4096 : 2048];  // 2 x 16/8 KB

    const int t = threadIdx.x;
    int bn, bm, bz;
    if (xcdmap) {
        const int lin = blockIdx.x;
        const int xc = lin & 7, j = lin >> 3;
        bz = xc + ((j >> 5) << 3);
        bm = j & 31;
        bn = 0;
    } else { bn = blockIdx.x; bm = blockIdx.y; bz = blockIdx.z; }
    const int batch = bz / ksplit;
    const int kz = bz - batch * ksplit;
    const int m0 = bm * 64, n0 = bn * 128;
    const int kb = kz * kchunk;
    const int ke = (kb + kchunk < K) ? (kb + kchunk) : K;
    const int nit = (ke - kb + 31) >> 5;

    const int lane = t & 63;
    const int w = t >> 6;
    const int wm = w >> 1, wn = w & 1;
    const int fr = lane & 15;
    const int fq = (lane >> 4) * 8;

    f4 acc[2][4];
#pragma unroll
    for (int mt = 0; mt < 2; ++mt)
#pragma unroll
        for (int nt = 0; nt < 4; ++nt) acc[mt][nt] = (f4){0.f, 0.f, 0.f, 0.f};

    const float* Ab = A + (long)batch * sA;
    const int mvalid = M - m0;

    // A staging: lane ra=t>>3 covers row ra (+32 for second issue), 16B chunks
    // XOR-swizzled in the global source so LDS stays linear.
    const int ra = t >> 3;
    const int ja = (t & 7) ^ (ra & 7);
    const float* aS0 = Ab + (long)(m0 + ra) * lda + 4 * ja;
    const float* aS1 = aS0 + 32L * lda;

    const __bf16* bTS0 = nullptr; const __bf16* bTS1 = nullptr;
    const float* bNS0 = nullptr;
    if constexpr (BMODE == 0) {
        const __bf16* BT = (const __bf16*)Bv + (long)batch * sB;
        const int nb = t >> 2;
        const int fb = (nb & 3) ^ ((nb >> 2) & 3);
        const int jb = (t & 3) ^ fb;
        bTS0 = BT + (long)(n0 + nb) * ldb + 8 * jb;
        bTS1 = bTS0 + 64L * ldb;
    } else {
        const float* Bn = (const float*)Bv + (long)batch * sB;
        bNS0 = Bn + (long)(t >> 5) * ldb + n0 + (t & 31) * 4;
    }

    auto STAGE = [&](int b, int k0) {
        if (ra < mvalid)      glds16(aS0 + k0, AsF[b] + 4 * t);
        if (ra + 32 < mvalid) glds16(aS1 + k0, AsF[b] + 1024 + 4 * t);
        if constexpr (BMODE == 0) {
            glds16(bTS0 + k0, Bbuf[b] + 4 * t);
            glds16(bTS1 + k0, Bbuf[b] + 1024 + 4 * t);
        } else {
            const float* bp = bNS0 + (long)k0 * ldb;
            glds16(bp,             Bbuf[b] + 4 * t);
            glds16(bp + 8L * ldb,  Bbuf[b] + 1024 + 4 * t);
            glds16(bp + 16L * ldb, Bbuf[b] + 2048 + 4 * t);
            glds16(bp + 24L * ldb, Bbuf[b] + 3072 + 4 * t);
        }
    };

    // frag-read offsets (constant across K)
    const int R0 = wm * 32 + fr, R1 = R0 + 16;
    const int jq = (lane >> 4) * 2;
    const int x7 = R0 & 7;
    const int aO00 = R0 * 8 + (jq ^ x7);
    const int aO01 = R0 * 8 + ((jq + 1) ^ x7);
    const int aO10 = R1 * 8 + (jq ^ x7);
    const int aO11 = R1 * 8 + ((jq + 1) ^ x7);
    int bOf[4];
    if constexpr (BMODE == 0) {
        const int fbc = (fr & 3) ^ ((fr >> 2) & 3);
        const int jb2 = (lane >> 4) ^ fbc;
#pragma unroll
        for (int nt = 0; nt < 4; ++nt)
            bOf[nt] = ((wn * 64 + nt * 16 + fr) * 4 + jb2) * 8;  // bf16 idx
    } else {
#pragma unroll
        for (int nt = 0; nt < 4; ++nt)
            bOf[nt] = wn * 64 + nt * 16 + fr;                    // col idx
    }

    STAGE(0, kb);
    __syncthreads();
    int cur = 0;
    for (int i = 0; i < nit; ++i) {
        if (i + 1 < nit) STAGE(cur ^ 1, kb + (i + 1) * 32);

        const float* Ac = AsF[cur];
        f4 x0 = *(const f4*)(Ac + aO00 * 4);
        f4 x1 = *(const f4*)(Ac + aO01 * 4);
        f4 x2 = *(const f4*)(Ac + aO10 * 4);
        f4 x3 = *(const f4*)(Ac + aO11 * 4);
        bf8_t af0, af1;
#pragma unroll
        for (int q = 0; q < 4; ++q) {
            af0[q] = (__bf16)x0[q]; af0[4 + q] = (__bf16)x1[q];
            af1[q] = (__bf16)x2[q]; af1[4 + q] = (__bf16)x3[q];
        }
#pragma unroll
        for (int nt = 0; nt < 4; ++nt) {
            bf8_t bv;
            if constexpr (BMODE == 0) {
                bv = *(const bf8_t*)((const __bf16*)Bbuf[cur] + bOf[nt]);
            } else {
                const float* bb = Bbuf[cur] + fq * 128 + bOf[nt];
#pragma unroll
                for (int d = 0; d < 8; ++d) bv[d] = (__bf16)bb[d * 128];
            }
            acc[0][nt] = __builtin_amdgcn_mfma_f32_16x16x32_bf16(af0, bv, acc[0][nt], 0, 0, 0);
            acc[1][nt] = __builtin_amdgcn_mfma_f32_16x16x32_bf16(af1, bv, acc[1][nt], 0, 0, 0);
        }
        __syncthreads();
        cur ^= 1;
    }

    float* Cp; long ldcp;
    const bool fin = (ksplit == 1);
    if (!fin) { Cp = C + (long)(batch * ksplit + kz) * M * N; ldcp = N; }
    else      { Cp = C + (long)batch * sC;                    ldcp = ldc; }

    const int rb = m0 + wm * 32 + (lane >> 4) * 4;
    const int cb_ = n0 + wn * 64 + fr;
#pragma unroll
    for (int mt = 0; mt < 2; ++mt) {
#pragma unroll
        for (int nt = 0; nt < 4; ++nt) {
            const int c = cb_ + nt * 16;
            const float bvl = (fin && bias) ? bias[c] : 0.f;
#pragma unroll
            for (int v = 0; v < 4; ++v) {
                const int r = rb + mt * 16 + v;
                if (r < M) {
                    float val = acc[mt][nt][v] + bvl;
                    if (fin && relu) val = fmaxf(val, 0.f);
                    if (fin && addsrc) val += addsrc[(long)r * ldcp + c];
                    Cp[(long)r * ldcp + c] = val;
                }
            }
        }
    }
}

// out[idx] = [relu](sum_z part[z*MN+idx] + bias[idx%N])
__global__ __launch_bounds__(256)
void reduce_splitk(const float* __restrict__ part, float* __restrict__ outp,
                   const float* __restrict__ bias, int MN, int N, int ksplit,
                   int relu) {
    int idx = blockIdx.x * 256 + threadIdx.x;
    if (idx >= MN) return;
    float s = 0.f;
    for (int z = 0; z < ksplit; ++z) s += part[(long)z * MN + idx];
    if (bias) s += bias[idx % N];
    if (relu) s = fmaxf(s, 0.f);
    outp[idx] = s;
}

// Fused GEMM1 reduce: h1 = relu(sum_z part + b_emb) + Q1; rs1 = rowsum(h1).
__global__ __launch_bounds__(256)
void reduce_rs_kernel(const float* __restrict__ part, float* __restrict__ h1,
                      const float* __restrict__ bias, const float* __restrict__ Q1,
                      float* __restrict__ rs1, int ksplit) {
    const int t = threadIdx.x;
    const int idx = blockIdx.x * 256 + t;
    float s = 0.f;
    for (int z = 0; z < ksplit; ++z) s += part[(long)z * 262144 + idx];
    s += bias[idx & 127];
    s = fmaxf(s, 0.f);
    s += Q1[idx & 16383];
    h1[idx] = s;
    float r = s;
    for (int off = 32; off > 0; off >>= 1) r += __shfl_down(r, off, 64);
    __shared__ float p[4];
    const int w = t >> 6, lane = t & 63;
    if (lane == 0) p[w] = r;
    __syncthreads();
    if (t < 2) rs1[(blockIdx.x << 1) + t] = p[t * 2] + p[t * 2 + 1];
}

// one wave per row: rs[r] = sum_j h[r*D + j]
__global__ __launch_bounds__(256)
void rowsum_kernel(const float* __restrict__ h, float* __restrict__ rs,
                   int rows, int D) {
    int gw = (blockIdx.x * 256 + threadIdx.x) >> 6;
    int lane = threadIdx.x & 63;
    if (gw >= rows) return;
    const float* p = h + (long)gw * D;
    float s = 0.f;
    for (int j = lane; j < D; j += 64) s += p[j];
    for (int off = 32; off > 0; off >>= 1) s += __shfl_down(s, off, 64);
    if (lane == 0) rs[gw] = s;
}

// ---------------------------------------------------------------------------
extern "C" void kernel_launch(void* const* d_in, const int* in_sizes, int n_in,
                              void* d_out, int out_size, void* d_ws, size_t ws_size,
                              hipStream_t stream) {
    const float* x       = (const float*)d_in[0];
    const float* W_emb   = (const float*)d_in[1];
    const float* b_emb   = (const float*)d_in[2];
    const float* W_pos1  = (const float*)d_in[3];
    const float* b_pos1  = (const float*)d_in[4];
    const float* W_red   = (const float*)d_in[5];
    const float* b_red   = (const float*)d_in[6];
    const float* W_pos2  = (const float*)d_in[7];
    const float* b_pos2  = (const float*)d_in[8];
    const float* W_red2  = (const float*)d_in[9];
    const float* b_red2  = (const float*)d_in[10];
    const float* W_pos3  = (const float*)d_in[11];
    const float* b_pos3  = (const float*)d_in[12];
    const float* W_down2 = (const float*)d_in[13];
    const float* b_down2 = (const float*)d_in[14];
    const float* W_flat  = (const float*)d_in[15];
    const float* b_flat  = (const float*)d_in[16];
    const float* W_d1    = (const float*)d_in[17];
    const float* b_d1    = (const float*)d_in[18];
    const float* W_d2    = (const float*)d_in[19];
    const float* b_d2    = (const float*)d_in[20];
    const float* W_d3    = (const float*)d_in[21];
    const float* b_d3    = (const float*)d_in[22];
    const float* W_p1    = (const float*)d_in[23];
    const float* b_p1    = (const float*)d_in[24];
    const float* W_p2    = (const float*)d_in[25];
    const float* b_p2    = (const float*)d_in[26];
    float* out = (float*)d_out;
    float* ws  = (float*)d_ws;

    size_t o = 0;
    auto alloc = [&](size_t n) { size_t p = o; o += (n + 63) & ~(size_t)63; return p; };
    const size_t oP1 = alloc(128 * 256);
    const size_t oP2 = alloc(128 * 512);
    const size_t oP3 = alloc(128 * 1280);
    const size_t oQ1 = alloc(128 * 128);
    const size_t oQ2 = alloc(128 * 256);
    const size_t oQ3 = alloc(128 * 640);
    const size_t oBC = alloc(32000);
    const size_t oH1 = alloc(2048 * 128);
    const size_t oRS1 = alloc(2048);
    const size_t oRS2 = alloc(2048);
    const size_t oH2 = alloc(2048 * 256);
    const size_t oH3 = alloc(2048 * 640);
    const size_t oH4 = alloc(2048 * 512);
    const size_t oH5 = alloc(16 * 512);
    const size_t oH6 = alloc(16 * 512);
    const size_t oH7 = alloc(16 * 512);
    const size_t oH8 = alloc(16 * 512);      // h68 = h6 + h8
    const size_t oM1 = alloc(16 * 32768);
    const size_t oM2 = alloc(16 * 163840);
    // bf16 transposed weights (sized in floats = bf16_count/2)
    const size_t oWembT = alloc(2048000);
    const size_t oWd2T  = alloc(163840);
    const size_t oQ1T   = alloc(16384);
    const size_t oQ2T   = alloc(65536);
    const size_t oQ3T   = alloc(409600);
    // partials: Q3(4x81920) -> GEMM1(32x262144) -> W_flat(64x8192) -> dense(...)
    const size_t oRegA = alloc(32u * 262144);
    const size_t oPartQ3 = oRegA, oPartG1 = oRegA, oPartF = oRegA;
    (void)ws_size; (void)in_sizes; (void)n_in; (void)out_size;

    __bf16* WembT = (__bf16*)(ws + oWembT);
    __bf16* Wd2T  = (__bf16*)(ws + oWd2T);
    __bf16* Q1T   = (__bf16*)(ws + oQ1T);
    __bf16* Q2T   = (__bf16*)(ws + oQ2T);
    __bf16* Q3T   = (__bf16*)(ws + oQ3T);

    dim3 blk(256);

    // 1. positional encodings + combined bias; weight transposes
    pos_enc_kernel<<<dim3(1149), blk, 0, stream>>>(ws + oP1, ws + oP2, ws + oP3,
                                                   b_p1, b_p2, ws + oBC);
    transpose_bf16_k<<<dim3(5280), blk, 0, stream>>>(W_emb, WembT, W_down2, Wd2T,
                                                     W_pos1, Q1T, W_pos2, Q2T,
                                                     W_pos3, Q3T);
    // 2-4. pos projections Q = relu(P @ W_pos + b)
    gemm_v2<0><<<dim3(1, 2, 1), blk, 0, stream>>>(ws + oP1, Q1T, ws + oQ1,
        b_pos1, nullptr, 128, 128, 256, 256, 256, 128, 0, 0, 0, 1, 256, 1, 0);
    gemm_v2<0><<<dim3(2, 2, 1), blk, 0, stream>>>(ws + oP2, Q2T, ws + oQ2,
        b_pos2, nullptr, 128, 256, 512, 512, 512, 256, 0, 0, 0, 1, 512, 1, 0);
    gemm_v2<0><<<dim3(5, 2, 4), blk, 0, stream>>>(ws + oP3, Q3T, ws + oPartQ3,
        nullptr, nullptr, 128, 640, 1280, 1280, 1280, 640, 0, 0, 0, 4, 320, 0, 0);
    reduce_splitk<<<dim3(320), blk, 0, stream>>>(ws + oPartQ3, ws + oQ3, b_pos3,
                                                 81920, 640, 4, 1);
    // 5. GEMM1: x(2048x32000) @ W_emb -> partials (split-K 32, XCD-grouped)
    gemm_v2<0><<<dim3(1024), blk, 0, stream>>>(x, WembT, ws + oPartG1,
        nullptr, nullptr, 2048, 128, 32000, 32000, 32000, 128, 0, 0, 0, 32, 1024, 0, 1);
    // 6. h1 = relu(sum + b_emb) + Q1 ; rs1 = rowsum(h1)
    reduce_rs_kernel<<<dim3(1024), blk, 0, stream>>>(ws + oPartG1, ws + oH1, b_emb,
                                                     ws + oQ1, ws + oRS1, 32);
    // 7. M1 = rs1(16x128) @ W_red viewed (128 x 32768)
    gemm_v2<1><<<dim3(256, 1, 1), blk, 0, stream>>>(ws + oRS1, W_red, ws + oM1,
        nullptr, nullptr, 16, 32768, 128, 128, 32768, 32768, 0, 0, 0, 1, 128, 0, 0);
    // 8. h2 = relu(h1[b] @ M1[b] + b_red) + Q2  (batched, fp32-natural B)
    gemm_v2<1><<<dim3(2, 2, 16), blk, 0, stream>>>(ws + oH1, ws + oM1, ws + oH2,
        b_red, ws + oQ2, 128, 256, 128, 128, 256, 256, 16384, 32768, 32768, 1, 128, 1, 0);
    // 9. rs2
    rowsum_kernel<<<dim3(512), blk, 0, stream>>>(ws + oH2, ws + oRS2, 2048, 256);
    // 10. M2 = rs2(16x128) @ W_red2 viewed (128 x 163840)
    gemm_v2<1><<<dim3(1280, 1, 1), blk, 0, stream>>>(ws + oRS2, W_red2, ws + oM2,
        nullptr, nullptr, 16, 163840, 128, 128, 163840, 163840, 0, 0, 0, 1, 128, 0, 0);
    // 11. h3 = relu(h2[b] @ M2[b] + b_red2) + Q3  (batched)
    gemm_v2<1><<<dim3(5, 2, 16), blk, 0, stream>>>(ws + oH2, ws + oM2, ws + oH3,
        b_red2, ws + oQ3, 128, 640, 256, 256, 640, 640, 32768, 163840, 81920, 1, 256, 1, 0);
    // 12. h4 = relu(h3 @ W_down2 + b_down2)
    gemm_v2<0><<<dim3(4, 32, 1), blk, 0, stream>>>(ws + oH3, Wd2T, ws + oH4,
        b_down2, nullptr, 2048, 512, 640, 640, 640, 512, 0, 0, 0, 1, 640, 1, 0);
    // 13-14. h5 = relu(h4 viewed (16x65536) @ W_flat + b_flat), split-K 64
    gemm_v2<1><<<dim3(4, 1, 64), blk, 0, stream>>>(ws + oH4, W_flat, ws + oPartF,
        nullptr, nullptr, 16, 512, 65536, 65536, 512, 512, 0, 0, 0, 64, 1024, 0, 0);
    reduce_splitk<<<dim3(32), blk, 0, stream>>>(ws + oPartF, ws + oH5, b_flat,
                                                8192, 512, 64, 1);
    // 15-17. dense chain (d3 fuses +h6 via addsrc -> h68)
    gemm_v2<1><<<dim3(4, 1, 1), blk, 0, stream>>>(ws + oH5, W_d1, ws + oH6,
        b_d1, nullptr, 16, 512, 512, 512, 512, 512, 0, 0, 0, 1, 512, 1, 0);
    gemm_v2<1><<<dim3(4, 1, 1), blk, 0, stream>>>(ws + oH6, W_d2, ws + oH7,
        b_d2, nullptr, 16, 512, 512, 512, 512, 512, 0, 0, 0, 1, 512, 1, 0);
    gemm_v2<1><<<dim3(4, 1, 1), blk, 0, stream>>>(ws + oH7, W_d3, ws + oH8,
        b_d3, ws + oH6, 16, 512, 512, 512, 512, 512, 0, 0, 0, 1, 512, 1, 0);
    // 18. out  = h68 @ W_p1 + (2*b_p1 + b_p2)
    gemm_v2<1><<<dim3(250, 1, 1), blk, 0, stream>>>(ws + oH8, W_p1, out,
        ws + oBC, nullptr, 16, 32000, 512, 512, 32000, 32000, 0, 0, 0, 1, 512, 0, 0);
    // 19. out += h7 @ W_p2
    gemm_v2<1><<<dim3(250, 1, 1), blk, 0, stream>>>(ws + oH7, W_p2, out,
        nullptr, out, 16, 32000, 512, 512, 32000, 32000, 0, 0, 0, 1, 512, 0, 0);
}

// Round 6
// 363.148 us; speedup vs baseline: 1.6528x; 1.2339x over previous
//
#include <hip/hip_runtime.h>

typedef float  f4   __attribute__((ext_vector_type(4)));
typedef __bf16 bf8_t __attribute__((ext_vector_type(8)));
typedef __bf16 bf4_t __attribute__((ext_vector_type(4)));

__device__ __forceinline__ void glds16(const void* g, void* l) {
    __builtin_amdgcn_global_load_lds(
        (const __attribute__((address_space(1))) void*)g,
        (__attribute__((address_space(3))) void*)l, 16, 0, 0);
}

// ---------------------------------------------------------------------------
// prep: weight transposes (blocks 0..5279) + pos encodings / combined bias /
// rs2 zero (blocks 5280..6436).
// ---------------------------------------------------------------------------
__global__ __launch_bounds__(256)
void prep_kernel(float* __restrict__ P1, float* __restrict__ P2,
                 float* __restrict__ P3,
                 const float* __restrict__ bp1, const float* __restrict__ bp2,
                 float* __restrict__ bc, float* __restrict__ rs2,
                 const float* __restrict__ Wemb, __bf16* __restrict__ WembT,
                 const float* __restrict__ Wd2, __bf16* __restrict__ Wd2T,
                 const float* __restrict__ Wq1, __bf16* __restrict__ Wq1T,
                 const float* __restrict__ Wq2, __bf16* __restrict__ Wq2T,
                 const float* __restrict__ Wq3, __bf16* __restrict__ Wq3T) {
    const int bid = blockIdx.x;
    const int t = threadIdx.x;
    if (bid < 5280) {
        const float* src; __bf16* dst; int CN, RK, tn, local;
        if (bid < 4000)      { src = Wemb; dst = WembT; RK = 32000; CN = 128; tn = 4;  local = bid; }
        else if (bid < 4320) { src = Wd2;  dst = Wd2T;  RK = 640;   CN = 512; tn = 16; local = bid - 4000; }
        else if (bid < 4352) { src = Wq1;  dst = Wq1T;  RK = 256;   CN = 128; tn = 4;  local = bid - 4320; }
        else if (bid < 4480) { src = Wq2;  dst = Wq2T;  RK = 512;   CN = 256; tn = 8;  local = bid - 4352; }
        else                 { src = Wq3;  dst = Wq3T;  RK = 1280;  CN = 640; tn = 20; local = bid - 4480; }
        const int kt = local / tn, ntl = local - kt * tn;
        const int k0 = kt * 32, n0 = ntl * 32;
        __shared__ float tile[32][33];
        const int r = t >> 3, c4 = (t & 7) * 4;
        const f4 v = *(const f4*)(src + (long)(k0 + r) * CN + n0 + c4);
        tile[r][c4] = v[0]; tile[r][c4 + 1] = v[1];
        tile[r][c4 + 2] = v[2]; tile[r][c4 + 3] = v[3];
        __syncthreads();
        bf4_t o2;
        o2[0] = (__bf16)tile[c4][r];     o2[1] = (__bf16)tile[c4 + 1][r];
        o2[2] = (__bf16)tile[c4 + 2][r]; o2[3] = (__bf16)tile[c4 + 3][r];
        *(bf4_t*)(dst + (long)(n0 + r) * RK + k0 + c4) = o2;
        return;
    }
    int idx = (bid - 5280) * 256 + t;
    const int n1 = 128 * 256, n2 = 128 * 512;      // P3: 128*1280
    const int nP = 262144;
    if (idx < nP) {
        float* P; int d, local;
        if (idx < n1)           { P = P1; d = 256;  local = idx; }
        else if (idx < n1 + n2) { P = P2; d = 512;  local = idx - n1; }
        else                    { P = P3; d = 1280; local = idx - n1 - n2; }
        int s = local / d;
        int k = local - s * d;
        int i = k >> 1;
        float ang = (float)s * powf(10000.0f, (-2.0f * (float)i) / (float)d);
        P[local] = (k & 1) ? cosf(ang) : sinf(ang);
    } else if (idx < nP + 32000) {
        int j = idx - nP;
        bc[j] = 2.f * bp1[j] + bp2[j];
    } else if (idx < nP + 32000 + 2048) {
        rs2[idx - nP - 32000] = 0.f;
    }
}

// ---------------------------------------------------------------------------
// Core MFMA GEMM device body (2-phase glds16 pipeline, proven in R5).
//   BMODE 0: B = bf16 [N][K] pre-transposed; BMODE 1: B = fp32 [K][N] natural
//            (with optional B2 switch at k >= kswitch, same ldb).
//   rsum != nullptr (ksplit==1 only): atomically adds final row sums into
//   rsum[bz*M + r] (rsum must be pre-zeroed).
// ---------------------------------------------------------------------------
template<int BMODE>
__device__ __forceinline__ void gemm_dev(
    float* As0, float* As1, float* Bb0, float* Bb1,
    const float* __restrict__ A, const void* __restrict__ Bv,
    const void* __restrict__ B2v, float* __restrict__ C,
    const float* __restrict__ bias, const float* __restrict__ addsrc,
    float* __restrict__ rsum,
    int M, int N, int K, int lda, int ldb, int ldc, int kswitch,
    long sA, long sB, long sC, int ksplit, int kchunk, int relu,
    int bn, int bm, int bz) {

    const int t = threadIdx.x;
    const int batch = bz / ksplit;
    const int kz = bz - batch * ksplit;
    const int m0 = bm * 64, n0 = bn * 128;
    const int kb = kz * kchunk;
    const int ke = (kb + kchunk < K) ? (kb + kchunk) : K;
    const int nit = (ke - kb + 31) >> 5;

    const int lane = t & 63;
    const int w = t >> 6;
    const int wm = w >> 1, wn = w & 1;
    const int fr = lane & 15;
    const int fq = (lane >> 4) * 8;

    f4 acc[2][4];
#pragma unroll
    for (int mt = 0; mt < 2; ++mt)
#pragma unroll
        for (int nt = 0; nt < 4; ++nt) acc[mt][nt] = (f4){0.f, 0.f, 0.f, 0.f};

    const float* Ab = A + (long)batch * sA;
    const int mvalid = M - m0;

    const int ra = t >> 3;
    const int ja = (t & 7) ^ (ra & 7);
    const float* aS0 = Ab + (long)(m0 + ra) * lda + 4 * ja;
    const float* aS1 = aS0 + 32L * lda;

    const __bf16* bTS0 = nullptr; const __bf16* bTS1 = nullptr;
    const float* bNS0 = nullptr; const float* bNS2 = nullptr;
    if constexpr (BMODE == 0) {
        const __bf16* BT = (const __bf16*)Bv + (long)batch * sB;
        const int nb = t >> 2;
        const int fb = (nb & 3) ^ ((nb >> 2) & 3);
        const int jb = (t & 3) ^ fb;
        bTS0 = BT + (long)(n0 + nb) * ldb + 8 * jb;
        bTS1 = bTS0 + 64L * ldb;
    } else {
        const float* Bn = (const float*)Bv + (long)batch * sB;
        bNS0 = Bn + (long)(t >> 5) * ldb + n0 + (t & 31) * 4;
        const float* Bn2 = (const float*)(B2v ? B2v : Bv);
        bNS2 = Bn2 + (long)(t >> 5) * ldb + n0 + (t & 31) * 4;
    }

    auto STAGE = [&](float* Ad, float* Bd, int k0) {
        if (ra < mvalid)      glds16(aS0 + k0, Ad + 4 * t);
        if (ra + 32 < mvalid) glds16(aS1 + k0, Ad + 1024 + 4 * t);
        if constexpr (BMODE == 0) {
            glds16(bTS0 + k0, Bd + 4 * t);
            glds16(bTS1 + k0, Bd + 1024 + 4 * t);
        } else {
            const float* bp = (k0 < kswitch) ? (bNS0 + (long)k0 * ldb)
                                             : (bNS2 + (long)(k0 - kswitch) * ldb);
            glds16(bp,             Bd + 4 * t);
            glds16(bp + 8L * ldb,  Bd + 1024 + 4 * t);
            glds16(bp + 16L * ldb, Bd + 2048 + 4 * t);
            glds16(bp + 24L * ldb, Bd + 3072 + 4 * t);
        }
    };

    // frag-read offsets (constant across K)
    const int R0 = wm * 32 + fr, R1 = R0 + 16;
    const int jq = (lane >> 4) * 2;
    const int x7 = R0 & 7;
    const int aO00 = R0 * 8 + (jq ^ x7);
    const int aO01 = R0 * 8 + ((jq + 1) ^ x7);
    const int aO10 = R1 * 8 + (jq ^ x7);
    const int aO11 = R1 * 8 + ((jq + 1) ^ x7);
    int bOf[4];
    if constexpr (BMODE == 0) {
        const int fbc = (fr & 3) ^ ((fr >> 2) & 3);
        const int jb2 = (lane >> 4) ^ fbc;
#pragma unroll
        for (int nt = 0; nt < 4; ++nt)
            bOf[nt] = ((wn * 64 + nt * 16 + fr) * 4 + jb2) * 8;  // bf16 idx
    } else {
#pragma unroll
        for (int nt = 0; nt < 4; ++nt)
            bOf[nt] = wn * 64 + nt * 16 + fr;                    // col idx
    }

    STAGE(As0, Bb0, kb);
    __syncthreads();
    int cur = 0;
    for (int i = 0; i < nit; ++i) {
        float* Ac = cur ? As1 : As0;
        float* Bc = cur ? Bb1 : Bb0;
        if (i + 1 < nit) STAGE(cur ? As0 : As1, cur ? Bb0 : Bb1, kb + (i + 1) * 32);

        f4 x0 = *(const f4*)(Ac + aO00 * 4);
        f4 x1 = *(const f4*)(Ac + aO01 * 4);
        f4 x2 = *(const f4*)(Ac + aO10 * 4);
        f4 x3 = *(const f4*)(Ac + aO11 * 4);
        bf8_t af0, af1;
#pragma unroll
        for (int q = 0; q < 4; ++q) {
            af0[q] = (__bf16)x0[q]; af0[4 + q] = (__bf16)x1[q];
            af1[q] = (__bf16)x2[q]; af1[4 + q] = (__bf16)x3[q];
        }
#pragma unroll
        for (int nt = 0; nt < 4; ++nt) {
            bf8_t bv;
            if constexpr (BMODE == 0) {
                bv = *(const bf8_t*)((const __bf16*)Bc + bOf[nt]);
            } else {
                const float* bb = Bc + fq * 128 + bOf[nt];
#pragma unroll
                for (int d = 0; d < 8; ++d) bv[d] = (__bf16)bb[d * 128];
            }
            acc[0][nt] = __builtin_amdgcn_mfma_f32_16x16x32_bf16(af0, bv, acc[0][nt], 0, 0, 0);
            acc[1][nt] = __builtin_amdgcn_mfma_f32_16x16x32_bf16(af1, bv, acc[1][nt], 0, 0, 0);
        }
        __syncthreads();
        cur ^= 1;
    }

    float* Cp; long ldcp;
    const bool fin = (ksplit == 1);
    if (!fin) { Cp = C + (long)(batch * ksplit + kz) * M * N; ldcp = N; }
    else      { Cp = C + (long)batch * sC;                    ldcp = ldc; }

    const int rb = m0 + wm * 32 + (lane >> 4) * 4;
    const int cb_ = n0 + wn * 64 + fr;
    float rowpart[2][4] = {{0.f,0.f,0.f,0.f},{0.f,0.f,0.f,0.f}};
#pragma unroll
    for (int mt = 0; mt < 2; ++mt) {
#pragma unroll
        for (int nt = 0; nt < 4; ++nt) {
            const int c = cb_ + nt * 16;
            const float bvl = (fin && bias) ? bias[c] : 0.f;
#pragma unroll
            for (int v = 0; v < 4; ++v) {
                const int r = rb + mt * 16 + v;
                if (r < M) {
                    float val = acc[mt][nt][v] + bvl;
                    if (fin && relu) val = fmaxf(val, 0.f);
                    if (fin && addsrc) val += addsrc[(long)r * ldcp + c];
                    Cp[(long)r * ldcp + c] = val;
                    rowpart[mt][v] += val;
                }
            }
        }
    }
    if (rsum) {
#pragma unroll
        for (int mt = 0; mt < 2; ++mt) {
#pragma unroll
            for (int v = 0; v < 4; ++v) {
                float s = rowpart[mt][v];
                s += __shfl_xor(s, 1); s += __shfl_xor(s, 2);
                s += __shfl_xor(s, 4); s += __shfl_xor(s, 8);
                const int r = rb + mt * 16 + v;
                if (fr == 0 && r < M) atomicAdd(&rsum[(long)bz * M + r], s);
            }
        }
    }
}

// Generic launch wrapper
template<int BMODE>
__global__ __launch_bounds__(256)
void gemm_v2(const float* A, const void* Bv, const void* B2v, float* C,
             const float* bias, const float* addsrc, float* rsum,
             int M, int N, int K, int lda, int ldb, int ldc, int kswitch,
             long sA, long sB, long sC, int ksplit, int kchunk, int relu) {
    __shared__ __align__(16) float AsF[2][2048];
    __shared__ __align__(16) float Bbuf[2][BMODE ? 4096 : 2048];
    gemm_dev<BMODE>(&AsF[0][0], &AsF[1][0], &Bbuf[0][0], &Bbuf[1][0],
                    A, Bv, B2v, C, bias, addsrc, rsum,
                    M, N, K, lda, ldb, ldc, kswitch, sA, sB, sC,
                    ksplit, kchunk, relu,
                    blockIdx.x, blockIdx.y, blockIdx.z);
}

// mega1: GEMM1 (1024 blocks, XCD-grouped split-K) + Q1 (2) + Q2 (4) + Q3 (10)
__global__ __launch_bounds__(256)
void mega1_kernel(const float* __restrict__ x, const __bf16* __restrict__ WembT,
                  float* __restrict__ partG1,
                  const float* __restrict__ P1, const __bf16* __restrict__ Q1T,
                  float* __restrict__ Q1o, const float* __restrict__ bq1,
                  const float* __restrict__ P2, const __bf16* __restrict__ Q2T,
                  float* __restrict__ Q2o, const float* __restrict__ bq2,
                  const float* __restrict__ P3, const __bf16* __restrict__ Q3T,
                  float* __restrict__ Q3o, const float* __restrict__ bq3) {
    __shared__ __align__(16) float AsF[2][2048];
    __shared__ __align__(16) float Bbuf[2][2048];
    float* A0 = &AsF[0][0]; float* A1 = &AsF[1][0];
    float* B0 = &Bbuf[0][0]; float* B1 = &Bbuf[1][0];
    const int bid = blockIdx.x;
    if (bid < 1024) {
        const int xc = bid & 7, j = bid >> 3;
        const int bz = xc + ((j >> 5) << 3);
        const int bm = j & 31;
        gemm_dev<0>(A0, A1, B0, B1, x, WembT, nullptr, partG1,
                    nullptr, nullptr, nullptr,
                    2048, 128, 32000, 32000, 32000, 128, 32000,
                    0, 0, 0, 32, 1024, 0, 0, bm, bz);
    } else if (bid < 1026) {
        gemm_dev<0>(A0, A1, B0, B1, P1, Q1T, nullptr, Q1o,
                    bq1, nullptr, nullptr,
                    128, 128, 256, 256, 256, 128, 256,
                    0, 0, 0, 1, 256, 1, 0, bid - 1024, 0);
    } else if (bid < 1030) {
        const int l = bid - 1026;
        gemm_dev<0>(A0, A1, B0, B1, P2, Q2T, nullptr, Q2o,
                    bq2, nullptr, nullptr,
                    128, 256, 512, 512, 512, 256, 512,
                    0, 0, 0, 1, 512, 1, l & 1, l >> 1, 0);
    } else {
        const int l = bid - 1030;
        gemm_dev<0>(A0, A1, B0, B1, P3, Q3T, nullptr, Q3o,
                    bq3, nullptr, nullptr,
                    128, 640, 1280, 1280, 1280, 640, 1280,
                    0, 0, 0, 1, 1280, 1, l % 5, l / 5, 0);
    }
}

// out[idx] = [relu](sum_z part[z*MN+idx] + bias[idx%N])
__global__ __launch_bounds__(256)
void reduce_splitk(const float* __restrict__ part, float* __restrict__ outp,
                   const float* __restrict__ bias, int MN, int N, int ksplit,
                   int relu) {
    int idx = blockIdx.x * 256 + threadIdx.x;
    if (idx >= MN) return;
    float s = 0.f;
    for (int z = 0; z < ksplit; ++z) s += part[(long)z * MN + idx];
    if (bias) s += bias[idx % N];
    if (relu) s = fmaxf(s, 0.f);
    outp[idx] = s;
}

// GEMM1 reduce: h1 = relu(sum_z part + b_emb) + Q1; rs1 = rowsum(h1).
__global__ __launch_bounds__(256)
void reduce_rs_kernel(const float* __restrict__ part, float* __restrict__ h1,
                      const float* __restrict__ bias, const float* __restrict__ Q1,
                      float* __restrict__ rs1, int ksplit) {
    const int t = threadIdx.x;
    const int idx = blockIdx.x * 256 + t;
    float s = 0.f;
    for (int z = 0; z < ksplit; ++z) s += part[(long)z * 262144 + idx];
    s += bias[idx & 127];
    s = fmaxf(s, 0.f);
    s += Q1[idx & 16383];
    h1[idx] = s;
    float r = s;
    for (int off = 32; off > 0; off >>= 1) r += __shfl_down(r, off, 64);
    __shared__ float p[4];
    const int w = t >> 6, lane = t & 63;
    if (lane == 0) p[w] = r;
    __syncthreads();
    if (t < 2) rs1[(blockIdx.x << 1) + t] = p[t * 2] + p[t * 2 + 1];
}

// ---------------------------------------------------------------------------
extern "C" void kernel_launch(void* const* d_in, const int* in_sizes, int n_in,
                              void* d_out, int out_size, void* d_ws, size_t ws_size,
                              hipStream_t stream) {
    const float* x       = (const float*)d_in[0];
    const float* W_emb   = (const float*)d_in[1];
    const float* b_emb   = (const float*)d_in[2];
    const float* W_pos1  = (const float*)d_in[3];
    const float* b_pos1  = (const float*)d_in[4];
    const float* W_red   = (const float*)d_in[5];
    const float* b_red   = (const float*)d_in[6];
    const float* W_pos2  = (const float*)d_in[7];
    const float* b_pos2  = (const float*)d_in[8];
    const float* W_red2  = (const float*)d_in[9];
    const float* b_red2  = (const float*)d_in[10];
    const float* W_pos3  = (const float*)d_in[11];
    const float* b_pos3  = (const float*)d_in[12];
    const float* W_down2 = (const float*)d_in[13];
    const float* b_down2 = (const float*)d_in[14];
    const float* W_flat  = (const float*)d_in[15];
    const float* b_flat  = (const float*)d_in[16];
    const float* W_d1    = (const float*)d_in[17];
    const float* b_d1    = (const float*)d_in[18];
    const float* W_d2    = (const float*)d_in[19];
    const float* b_d2    = (const float*)d_in[20];
    const float* W_d3    = (const float*)d_in[21];
    const float* b_d3    = (const float*)d_in[22];
    const float* W_p1    = (const float*)d_in[23];
    const float* b_p1    = (const float*)d_in[24];
    const float* W_p2    = (const float*)d_in[25];
    const float* b_p2    = (const float*)d_in[26];
    float* out = (float*)d_out;
    float* ws  = (float*)d_ws;

    size_t o = 0;
    auto alloc = [&](size_t n) { size_t p = o; o += (n + 63) & ~(size_t)63; return p; };
    const size_t oP1 = alloc(128 * 256);
    const size_t oP2 = alloc(128 * 512);
    const size_t oP3 = alloc(128 * 1280);
    const size_t oQ1 = alloc(128 * 128);
    const size_t oQ2 = alloc(128 * 256);
    const size_t oQ3 = alloc(128 * 640);
    const size_t oBC = alloc(32000);
    const size_t oH1 = alloc(2048 * 128);
    const size_t oRS1 = alloc(2048);
    const size_t oRS2 = alloc(2048);
    const size_t oH2 = alloc(2048 * 256);
    const size_t oH3 = alloc(2048 * 640);
    const size_t oH4 = alloc(2048 * 512);
    const size_t oH5 = alloc(16 * 512);
    const size_t oH6c = alloc(16 * 1024);    // h6 at stride 1024 (cols 0..511)
    const size_t oCat = alloc(16 * 1024);    // [h68 | h7] concat, stride 1024
    const size_t oM1 = alloc(16 * 32768);
    const size_t oM2 = alloc(16 * 163840);
    const size_t oWembT = alloc(2048000);    // bf16 buffers sized in floats
    const size_t oWd2T  = alloc(163840);
    const size_t oQ1T   = alloc(16384);
    const size_t oQ2T   = alloc(65536);
    const size_t oQ3T   = alloc(409600);
    const size_t oRegA = alloc(32u * 262144); // partials: GEMM1 / W_flat
    const size_t oPartG1 = oRegA, oPartF = oRegA;
    (void)ws_size; (void)in_sizes; (void)n_in; (void)out_size;

    __bf16* WembT = (__bf16*)(ws + oWembT);
    __bf16* Wd2T  = (__bf16*)(ws + oWd2T);
    __bf16* Q1T   = (__bf16*)(ws + oQ1T);
    __bf16* Q2T   = (__bf16*)(ws + oQ2T);
    __bf16* Q3T   = (__bf16*)(ws + oQ3T);

    dim3 blk(256);

    // 1. prep: transposes + pos encodings + combined bias + rs2 zero
    prep_kernel<<<dim3(6437), blk, 0, stream>>>(
        ws + oP1, ws + oP2, ws + oP3, b_p1, b_p2, ws + oBC, ws + oRS2,
        W_emb, WembT, W_down2, Wd2T, W_pos1, Q1T, W_pos2, Q2T, W_pos3, Q3T);
    // 2. mega1: GEMM1 partials + Q1 + Q2 + Q3 (one launch)
    mega1_kernel<<<dim3(1040), blk, 0, stream>>>(
        x, WembT, ws + oPartG1,
        ws + oP1, Q1T, ws + oQ1, b_pos1,
        ws + oP2, Q2T, ws + oQ2, b_pos2,
        ws + oP3, Q3T, ws + oQ3, b_pos3);
    // 3. h1 = relu(sum + b_emb) + Q1 ; rs1 = rowsum(h1)
    reduce_rs_kernel<<<dim3(1024), blk, 0, stream>>>(ws + oPartG1, ws + oH1,
                                                     b_emb, ws + oQ1, ws + oRS1, 32);
    // 4. M1 = rs1(16x128) @ W_red viewed (128 x 32768)
    gemm_v2<1><<<dim3(256, 1, 1), blk, 0, stream>>>(ws + oRS1, W_red, nullptr,
        ws + oM1, nullptr, nullptr, nullptr,
        16, 32768, 128, 128, 32768, 32768, 128, 0, 0, 0, 1, 128, 0);
    // 5. h2 = relu(h1[b] @ M1[b] + b_red) + Q2 ; rs2 += rowsums (atomic)
    gemm_v2<1><<<dim3(2, 2, 16), blk, 0, stream>>>(ws + oH1, ws + oM1, nullptr,
        ws + oH2, b_red, ws + oQ2, ws + oRS2,
        128, 256, 128, 128, 256, 256, 128, 16384, 32768, 32768, 1, 128, 1);
    // 6. M2 = rs2(16x128) @ W_red2 viewed (128 x 163840)
    gemm_v2<1><<<dim3(1280, 1, 1), blk, 0, stream>>>(ws + oRS2, W_red2, nullptr,
        ws + oM2, nullptr, nullptr, nullptr,
        16, 163840, 128, 128, 163840, 163840, 128, 0, 0, 0, 1, 128, 0);
    // 7. h3 = relu(h2[b] @ M2[b] + b_red2) + Q3
    gemm_v2<1><<<dim3(5, 2, 16), blk, 0, stream>>>(ws + oH2, ws + oM2, nullptr,
        ws + oH3, b_red2, ws + oQ3, nullptr,
        128, 640, 256, 256, 640, 640, 256, 32768, 163840, 81920, 1, 256, 1);
    // 8. h4 = relu(h3 @ W_down2 + b_down2)
    gemm_v2<0><<<dim3(4, 32, 1), blk, 0, stream>>>(ws + oH3, Wd2T, nullptr,
        ws + oH4, b_down2, nullptr, nullptr,
        2048, 512, 640, 640, 640, 512, 640, 0, 0, 0, 1, 640, 1);
    // 9. h5 partials = h4 viewed (16x65536) @ W_flat, split-K 64
    gemm_v2<1><<<dim3(4, 1, 64), blk, 0, stream>>>(ws + oH4, W_flat, nullptr,
        ws + oPartF, nullptr, nullptr, nullptr,
        16, 512, 65536, 65536, 512, 512, 65536, 0, 0, 0, 64, 1024, 0);
    // 10. h5 = relu(sum + b_flat)
    reduce_splitk<<<dim3(32), blk, 0, stream>>>(ws + oPartF, ws + oH5, b_flat,
                                                8192, 512, 64, 1);
    // 11-13. dense chain into stride-1024 concat layout
    gemm_v2<1><<<dim3(4, 1, 1), blk, 0, stream>>>(ws + oH5, W_d1, nullptr,
        ws + oH6c, b_d1, nullptr, nullptr,
        16, 512, 512, 512, 512, 1024, 512, 0, 0, 0, 1, 512, 1);
    gemm_v2<1><<<dim3(4, 1, 1), blk, 0, stream>>>(ws + oH6c, W_d2, nullptr,
        ws + oCat + 512, b_d2, nullptr, nullptr,
        16, 512, 512, 1024, 512, 1024, 512, 0, 0, 0, 1, 512, 1);
    gemm_v2<1><<<dim3(4, 1, 1), blk, 0, stream>>>(ws + oCat + 512, W_d3, nullptr,
        ws + oCat, b_d3, ws + oH6c, nullptr,
        16, 512, 512, 1024, 512, 1024, 512, 0, 0, 0, 1, 512, 1);
    // 14. out = [h68|h7](16x1024) @ [W_p1;W_p2](1024x32000) + (2*b_p1+b_p2)
    gemm_v2<1><<<dim3(250, 1, 1), blk, 0, stream>>>(ws + oCat, W_p1, W_p2,
        out, ws + oBC, nullptr, nullptr,
        16, 32000, 1024, 1024, 32000, 32000, 512, 0, 0, 0, 1, 1024, 0);
}